// Round 5
// baseline (800.209 us; speedup 1.0000x reference)
//
#include <hip/hip_runtime.h>

#define S 2048
#define Dh 128
#define NB 16
#define OUT_ELEMS ((size_t)NB * S * Dh)   // 4194304 floats (16 MB region before attn)
#define NEG_BIG -1.0e9f
#define SCALE 0.08838834764831845f        // 1/sqrt(128)

typedef __attribute__((ext_vector_type(8))) short bf16x8;
typedef __attribute__((ext_vector_type(4))) float f32x4;
typedef __attribute__((ext_vector_type(4))) short s16x4;

__device__ __forceinline__ short f2bf(float x) {
    unsigned u = __float_as_uint(x);
    u += 0x7fffu + ((u >> 16) & 1u);      // RNE truncate to bf16 (no NaN inputs here)
    return (short)(u >> 16);
}

__device__ __forceinline__ s16x4 pack4(float4 v) {
    s16x4 r;
    r.x = f2bf(v.x); r.y = f2bf(v.y); r.z = f2bf(v.z); r.w = f2bf(v.w);
    return r;
}

// ---------------------------------------------------------------------------
// Standalone prep kernels (fallback path uses these individually).
// ---------------------------------------------------------------------------
__global__ void detect_mask(const unsigned char* __restrict__ m, int* __restrict__ flag) {
    __shared__ int any;
    if (threadIdx.x == 0) any = 0;
    __syncthreads();
    int t = threadIdx.x;
    unsigned char v = (unsigned char)(m[t * 4 + 1] | m[t * 4 + 2] | m[t * 4 + 3]);
    if (v) atomicOr(&any, 1);
    __syncthreads();
    if (t == 0) *flag = any;
}

__device__ __forceinline__ void transpose_v_body(const float* __restrict__ V,
                                                 short* __restrict__ Vt,
                                                 int kb, int b, int t,
                                                 float (*Ls)[132]) {
    const float* Vb = V + ((size_t)b * S + kb * 64) * Dh;
    short* VtB = Vt + (size_t)b * Dh * S;
#pragma unroll
    for (int i = 0; i < 8; i++) {
        int idx = t + i * 256;
        int r = idx >> 5, c = (idx & 31) << 2;
        *(float4*)&Ls[r][c] = *(const float4*)(Vb + r * Dh + c);
    }
    __syncthreads();
#pragma unroll
    for (int i = 0; i < 8; i++) {
        int idx = t + i * 256;
        int n = idx >> 4, kc = (idx & 15) << 2;
        s16x4 o;
        o.x = f2bf(Ls[kc + 0][n]);
        o.y = f2bf(Ls[kc + 1][n]);
        o.z = f2bf(Ls[kc + 2][n]);
        o.w = f2bf(Ls[kc + 3][n]);
        *(s16x4*)(VtB + (size_t)n * S + kb * 64 + kc) = o;
    }
}

__global__ __launch_bounds__(256) void transpose_v(const float* __restrict__ V,
                                                   short* __restrict__ Vt) {
    __shared__ float Ls[64][132];
    transpose_v_body(V, Vt, blockIdx.x, blockIdx.y, threadIdx.x, Ls);
}

__device__ __forceinline__ void cvt_body(const float* __restrict__ in,
                                         short* __restrict__ out,
                                         int vbid, int nblk, int t) {
    const size_t n4 = (size_t)NB * S * Dh / 4;
    for (size_t i = (size_t)vbid * 256 + t; i < n4; i += (size_t)nblk * 256) {
        float4 v = ((const float4*)in)[i];
        ((s16x4*)out)[i] = pack4(v);
    }
}

__global__ __launch_bounds__(256) void cvt_bf16(const float* __restrict__ in,
                                                short* __restrict__ out) {
    cvt_body(in, out, blockIdx.x, gridDim.x, threadIdx.x);
}

// ---------------------------------------------------------------------------
// Merged prep: [0,512) transpose_v, [512,1024) cvt Q, [1024,1536) cvt K,
// 1536 detect_mask. One launch instead of four.
// ---------------------------------------------------------------------------
__global__ __launch_bounds__(256) void prep(const float* __restrict__ Q,
                                            const float* __restrict__ Km,
                                            const float* __restrict__ V,
                                            const unsigned char* __restrict__ M,
                                            short* __restrict__ Qbf,
                                            short* __restrict__ Kbf,
                                            short* __restrict__ Vt,
                                            int* __restrict__ flag) {
    __shared__ float Ls[64][132];
    __shared__ int any;
    const int bid = blockIdx.x, t = threadIdx.x;
    if (bid < 512) {
        transpose_v_body(V, Vt, bid & 31, bid >> 5, t, Ls);
    } else if (bid < 1024) {
        cvt_body(Q, Qbf, bid - 512, 512, t);
    } else if (bid < 1536) {
        cvt_body(Km, Kbf, bid - 1024, 512, t);
    } else {
        if (t == 0) any = 0;
        __syncthreads();
        unsigned char v = (unsigned char)(M[t * 4 + 1] | M[t * 4 + 2] | M[t * 4 + 3]);
        if (v) atomicOr(&any, 1);
        __syncthreads();
        if (t == 0) *flag = any;
    }
}

// ---------------------------------------------------------------------------
// PASS 1 (flash, barrier-free): per 64-row Q-tile, loop kt: QK -> mask ->
// online softmax -> P bf16 (wave-private LDS bounce) -> PV accumulate.
// Writes out (16 MB) + per-row stats (M, 1/L).
// Rows-per-wave: wave w owns rows mo=w*16..mo+15; Q frags live in 4 regs;
// K/Vt fragments read directly from L2-hot bf16 buffers (16 x 64B segments
// per instr). Mask + P staging are wave-private LDS -> ZERO __syncthreads.
// grid: 512 1-D blocks, XCD-grouped (b,qt) decode; 26 KB LDS.
// ---------------------------------------------------------------------------
__global__ __launch_bounds__(256, 2) void flash_pv(const short* __restrict__ Qbf,
                                                   const short* __restrict__ Kbf,
                                                   const short* __restrict__ Vt,
                                                   const void* __restrict__ maskp,
                                                   const int* __restrict__ flagp,
                                                   float2* __restrict__ stats,
                                                   float* __restrict__ Out) {
    // bid = k*8 + xcd, xcd = b>>1, k = (b&1)*32 + qt  (bijective; 2 batches/XCD)
    const int bid = blockIdx.x;
    const int xcd = bid & 7, kk = bid >> 3;
    const int b = xcd * 2 + (kk >> 5), qt = kk & 31;

    const short* QbfB = Qbf + ((size_t)b * S + qt * 64) * Dh;
    const short* KbfB = Kbf + (size_t)b * S * Dh;
    const short* VtB  = Vt  + (size_t)b * Dh * S;
    float* OutB = Out + ((size_t)b * S + qt * 64) * Dh;
    const int flag = *flagp;

    __shared__ short Ps[2][64][72];                      // 18 KB (wave-private rows)
    __shared__ __align__(16) unsigned char Msk[64][128]; // 8 KB  (wave-private rows)

    const int t = threadIdx.x, w = t >> 6, lane = t & 63, fr = lane & 15, quad = lane >> 4;
    const int mo = w * 16;

    // Q fragments: constant over kt, 4 x bf16x8 per lane.
    bf16x8 af[4];
#pragma unroll
    for (int ks = 0; ks < 4; ks++)
        af[ks] = *(const bf16x8*)(QbfB + (size_t)(mo + fr) * Dh +
                                  (ks >> 1) * 64 + (ks & 1) * 32 + quad * 8);

    float m[4], l[4];
#pragma unroll
    for (int r = 0; r < 4; r++) { m[r] = -3.4e38f; l[r] = 0.f; }
    f32x4 acc_o[8] = {};

    // wave-private mask staging coordinates: lane covers row mo+(lane>>2),
    // byte columns (lane&3)*32 .. +31
    const int mrow = mo + (lane >> 2);
    const int mcol = (lane & 3) * 32;
    const size_t mask_row_base = ((size_t)b * S + qt * 64 + mrow) * S;

    for (int kt = 0; kt < 16; kt++) {
        // ---- stage this kt's mask tile (wave-private; no barrier) ----
        if (flag) {   // uint8 mask
            const unsigned char* Mb = (const unsigned char*)maskp + mask_row_base + (size_t)kt * 128 + mcol;
            int4 a0 = *(const int4*)(Mb);
            int4 a1 = *(const int4*)(Mb + 16);
            *(int4*)&Msk[mrow][mcol]      = a0;
            *(int4*)&Msk[mrow][mcol + 16] = a1;
        } else {      // int32 mask
            const int* Mb = (const int*)maskp + mask_row_base + (size_t)kt * 128 + mcol;
#pragma unroll
            for (int j = 0; j < 8; j++) {
                int4 mv = *(const int4*)(Mb + j * 4);
                uchar4 o;
                o.x = (unsigned char)(mv.x != 0);
                o.y = (unsigned char)(mv.y != 0);
                o.z = (unsigned char)(mv.z != 0);
                o.w = (unsigned char)(mv.w != 0);
                *(uchar4*)&Msk[mrow][mcol + j * 4] = o;
            }
        }

        // ---- QK^T: wave rows mo..mo+15 x 128 cols; K frags from L2 ----
        f32x4 acc_s[8] = {};
#pragma unroll
        for (int ks = 0; ks < 4; ks++) {
            const int colk = (ks >> 1) * 64 + (ks & 1) * 32 + quad * 8;
            bf16x8 bfv[8];
#pragma unroll
            for (int ni = 0; ni < 8; ni++)
                bfv[ni] = *(const bf16x8*)(KbfB + (size_t)(kt * 128 + ni * 16 + fr) * Dh + colk);
#pragma unroll
            for (int ni = 0; ni < 8; ni++)
                acc_s[ni] = __builtin_amdgcn_mfma_f32_16x16x32_bf16(af[ks], bfv[ni], acc_s[ni], 0, 0, 0);
        }

        // ---- online-softmax epilogue, per owned row ----
#pragma unroll
        for (int r = 0; r < 4; r++) {
            const int row = mo + quad * 4 + r;
            float s[8];
#pragma unroll
            for (int ni = 0; ni < 8; ni++) {
                float v = acc_s[ni][r] * SCALE;
                if (Msk[row][ni * 16 + fr]) v = NEG_BIG;
                s[ni] = v;
            }
            float mx = s[0];
#pragma unroll
            for (int ni = 1; ni < 8; ni++) mx = fmaxf(mx, s[ni]);
#pragma unroll
            for (int o = 8; o > 0; o >>= 1) mx = fmaxf(mx, __shfl_xor(mx, o, 64));
            const float mn = fmaxf(m[r], mx);
            const float f = __expf(m[r] - mn);   // 0 on first tile (m = -3.4e38)
            float p[8], lt = 0.f;
#pragma unroll
            for (int ni = 0; ni < 8; ni++) { p[ni] = __expf(s[ni] - mn); lt += p[ni]; }
#pragma unroll
            for (int o = 8; o > 0; o >>= 1) lt += __shfl_xor(lt, o, 64);
            l[r] = l[r] * f + lt;
            m[r] = mn;
#pragma unroll
            for (int ni = 0; ni < 8; ni++) acc_o[ni][r] *= f;
#pragma unroll
            for (int ni = 0; ni < 8; ni++) {
                const int col = ni * 16 + fr;
                Ps[col >> 6][row][col & 63] = f2bf(p[ni]);
            }
        }

        // ---- PV: wave-private Ps reads + Vt frags from L2 ----
#pragma unroll
        for (int ks = 0; ks < 4; ks++) {
            bf16x8 paf = *(const bf16x8*)&Ps[ks >> 1][mo + fr][(ks & 1) * 32 + quad * 8];
            bf16x8 pb[8];
#pragma unroll
            for (int ni = 0; ni < 8; ni++)
                pb[ni] = *(const bf16x8*)(VtB + (size_t)(ni * 16 + fr) * S + kt * 128 + ks * 32 + quad * 8);
#pragma unroll
            for (int ni = 0; ni < 8; ni++)
                acc_o[ni] = __builtin_amdgcn_mfma_f32_16x16x32_bf16(paf, pb[ni], acc_o[ni], 0, 0, 0);
        }
    }

    float invl[4];
#pragma unroll
    for (int r = 0; r < 4; r++) invl[r] = 1.0f / l[r];
#pragma unroll
    for (int ni = 0; ni < 8; ni++)
#pragma unroll
        for (int r = 0; r < 4; r++) {
            const int row = mo + quad * 4 + r;
            OutB[(size_t)row * Dh + ni * 16 + fr] = acc_o[ni][r] * invl[r];
        }
    if (fr == 0) {
#pragma unroll
        for (int r = 0; r < 4; r++)
            stats[(size_t)b * S + qt * 64 + mo + quad * 4 + r] = make_float2(m[r], invl[r]);
    }
}

// ---------------------------------------------------------------------------
// PASS 2 (barrier-free): fully-parallel attn writer. 128x128 tiles,
// recompute QK^T (same ks-ascending accumulation order as flash_pv), mask,
// p = exp(s-M)*invL, store attn. Q/K fragments direct from L2; wave-private
// mask staging (16 KB LDS); zero __syncthreads in the u8 path.
// Rows-per-wave: wave w owns rows mw=w*32..mw+31.
// grid: 4096 1-D blocks, XCD-grouped (b,qt,kt) decode.
// ---------------------------------------------------------------------------
__global__ __launch_bounds__(256, 2) void attn_write(const short* __restrict__ Qbf,
                                                     const short* __restrict__ Kbf,
                                                     const void* __restrict__ maskp,
                                                     const int* __restrict__ flagp,
                                                     const float2* __restrict__ stats,
                                                     float* __restrict__ Attn) {
    // bid = k*8 + xcd, xcd = b>>1, k = (b&1)*256 + qt*16 + kt  (bijective)
    const int bid = blockIdx.x;
    const int xcd = bid & 7, kk = bid >> 3;
    const int b = xcd * 2 + (kk >> 8), rem = kk & 255, qt = rem >> 4, kt = rem & 15;

    const short* QbfB = Qbf + ((size_t)b * S + qt * 128) * Dh;
    const short* KbfB = Kbf + ((size_t)b * S + kt * 128) * Dh;
    const int flag = *flagp;

    __shared__ __align__(16) unsigned char Msk[128][128];   // 16 KB, wave-private rows

    const int t = threadIdx.x, w = t >> 6, lane = t & 63, fr = lane & 15, quad = lane >> 4;
    const int mw = w * 32;

    // ---- wave-private mask staging: rows mw..mw+31 ----
    {
        const int mcol = (lane & 3) * 32;
        if (flag) {   // uint8 mask
#pragma unroll
            for (int i = 0; i < 2; i++) {
                const int row = mw + i * 16 + (lane >> 2);
                const unsigned char* Mb = (const unsigned char*)maskp +
                    ((size_t)b * S + qt * 128 + row) * S + (size_t)kt * 128 + mcol;
                int4 a0 = *(const int4*)(Mb);
                int4 a1 = *(const int4*)(Mb + 16);
                *(int4*)&Msk[row][mcol]      = a0;
                *(int4*)&Msk[row][mcol + 16] = a1;
            }
        } else {      // int32 mask
#pragma unroll
            for (int i = 0; i < 2; i++) {
                const int row = mw + i * 16 + (lane >> 2);
                const int* Mb = (const int*)maskp +
                    ((size_t)b * S + qt * 128 + row) * S + (size_t)kt * 128 + mcol;
#pragma unroll
                for (int j = 0; j < 8; j++) {
                    int4 mv = *(const int4*)(Mb + j * 4);
                    uchar4 o;
                    o.x = (unsigned char)(mv.x != 0);
                    o.y = (unsigned char)(mv.y != 0);
                    o.z = (unsigned char)(mv.z != 0);
                    o.w = (unsigned char)(mv.w != 0);
                    *(uchar4*)&Msk[row][mcol + j * 4] = o;
                }
            }
        }
    }

    // ---- Q fragments (persistent) ----
    bf16x8 qf[2][4];
#pragma unroll
    for (int mi = 0; mi < 2; mi++)
#pragma unroll
        for (int ks = 0; ks < 4; ks++)
            qf[mi][ks] = *(const bf16x8*)(QbfB + (size_t)(mw + mi * 16 + fr) * Dh +
                                          (ks >> 1) * 64 + (ks & 1) * 32 + quad * 8);

    // ---- QK^T ----
    f32x4 acc[2][8] = {};
#pragma unroll
    for (int ks = 0; ks < 4; ks++) {
        const int colk = (ks >> 1) * 64 + (ks & 1) * 32 + quad * 8;
        bf16x8 kf[8];
#pragma unroll
        for (int ni = 0; ni < 8; ni++)
            kf[ni] = *(const bf16x8*)(KbfB + (size_t)(ni * 16 + fr) * Dh + colk);
#pragma unroll
        for (int mi = 0; mi < 2; mi++)
#pragma unroll
            for (int ni = 0; ni < 8; ni++)
                acc[mi][ni] = __builtin_amdgcn_mfma_f32_16x16x32_bf16(qf[mi][ks], kf[ni], acc[mi][ni], 0, 0, 0);
    }

    // ---- epilogue: mask, p = exp(s-M)*invL, store ----
    float* AttnB = Attn + (size_t)b * S * S;
#pragma unroll
    for (int mi = 0; mi < 2; mi++) {
        float2 st[4];
#pragma unroll
        for (int r = 0; r < 4; r++)
            st[r] = stats[(size_t)b * S + qt * 128 + mw + mi * 16 + quad * 4 + r];
#pragma unroll
        for (int ni = 0; ni < 8; ni++)
#pragma unroll
            for (int r = 0; r < 4; r++) {
                const int lrow = mw + mi * 16 + quad * 4 + r;
                const int lcol = ni * 16 + fr;
                float v = acc[mi][ni][r] * SCALE;
                if (Msk[lrow][lcol]) v = NEG_BIG;
                const float p = __expf(v - st[r].x) * st[r].y;
                AttnB[(size_t)(qt * 128 + lrow) * S + kt * 128 + lcol] = p;
            }
    }
}

// ===========================================================================
// FALLBACK PATH (verified round-2 kernels, used when ws is too small)
// ===========================================================================
__global__ __launch_bounds__(256) void reduce_stats(const float2* __restrict__ part,
                                                    float2* __restrict__ stats) {
    const int rid = blockIdx.x * 256 + threadIdx.x;   // [0, NB*S)
    const int b = rid >> 11, row = rid & (S - 1);
    float2 p[16];
    float M = -3.4e38f;
#pragma unroll
    for (int kt = 0; kt < 16; kt++) {
        p[kt] = part[((size_t)(b * 16 + kt)) * S + row];
        M = fmaxf(M, p[kt].x);
    }
    float L = 0.f;
#pragma unroll
    for (int kt = 0; kt < 16; kt++) L += p[kt].y * __expf(p[kt].x - M);
    stats[rid] = make_float2(M, 1.0f / L);
}

__global__ __launch_bounds__(256, 2) void qk_kernel(const float* __restrict__ Q,
                                                    const float* __restrict__ Km,
                                                    float* __restrict__ Sc,
                                                    const void* __restrict__ maskp,
                                                    const int* __restrict__ flagp,
                                                    float2* __restrict__ part,
                                                    const int fuse) {
    const int kt = blockIdx.x, qt = blockIdx.y, b = blockIdx.z;
    const float* Qb = Q + ((size_t)b * S + qt * 128) * Dh;
    const float* Kb = Km + ((size_t)b * S + kt * 128) * Dh;
    __shared__ short As[128][72];
    __shared__ short Bs[128][72];
    __shared__ __align__(16) unsigned char Ms[128][144];
    const int t = threadIdx.x;
    const int w = t >> 6, lane = t & 63, fr = lane & 15, quad = lane >> 4;
    const int mw = (w >> 1) * 64, nw = (w & 1) * 64;
    f32x4 acc[4][4] = {};

    if (fuse) {
        const int flag = *flagp;
        if (flag) {
            const unsigned char* Mb = (const unsigned char*)maskp + ((size_t)b * S + qt * 128) * S + (size_t)kt * 128;
#pragma unroll
            for (int i = 0; i < 4; i++) {
                int idx = t + i * 256;
                int r = idx >> 3, c = (idx & 7) * 16;
                *(int4*)&Ms[r][c] = *(const int4*)(Mb + (size_t)r * S + c);
            }
        } else {
            const int* Mb = (const int*)maskp + ((size_t)b * S + qt * 128) * S + (size_t)kt * 128;
#pragma unroll
            for (int i = 0; i < 16; i++) {
                int idx = t + i * 256;
                int r = idx >> 5, c = (idx & 31) * 4;
                int4 mv = *(const int4*)(Mb + (size_t)r * S + c);
                uchar4 o;
                o.x = (unsigned char)(mv.x != 0);
                o.y = (unsigned char)(mv.y != 0);
                o.z = (unsigned char)(mv.z != 0);
                o.w = (unsigned char)(mv.w != 0);
                *(uchar4*)&Ms[r][c] = o;
            }
        }
    }

    for (int k0 = 0; k0 < Dh; k0 += 64) {
        __syncthreads();
#pragma unroll
        for (int i = 0; i < 8; i++) {
            int idx = t + i * 256;
            int r = idx >> 4, c = (idx & 15) << 2;
            float4 qv = *(const float4*)(Qb + r * Dh + k0 + c);
            float4 kv = *(const float4*)(Kb + r * Dh + k0 + c);
            *(s16x4*)&As[r][c] = pack4(qv);
            *(s16x4*)&Bs[r][c] = pack4(kv);
        }
        __syncthreads();
#pragma unroll
        for (int kc = 0; kc < 2; kc++) {
            const int ko = kc * 32 + quad * 8;
            bf16x8 af[4], bf[4];
#pragma unroll
            for (int mi = 0; mi < 4; mi++) af[mi] = *(const bf16x8*)&As[mw + mi * 16 + fr][ko];
#pragma unroll
            for (int ni = 0; ni < 4; ni++) bf[ni] = *(const bf16x8*)&Bs[nw + ni * 16 + fr][ko];
#pragma unroll
            for (int mi = 0; mi < 4; mi++)
#pragma unroll
                for (int ni = 0; ni < 4; ni++)
                    acc[mi][ni] = __builtin_amdgcn_mfma_f32_16x16x32_bf16(af[mi], bf[ni], acc[mi][ni], 0, 0, 0);
        }
    }

    __syncthreads();
    float2* pm = (float2*)&As[0][0];
    float* ScB = Sc + (size_t)b * S * S;
#pragma unroll
    for (int mi = 0; mi < 4; mi++)
#pragma unroll
        for (int r = 0; r < 4; r++) {
            const int lrow = mw + mi * 16 + quad * 4 + r;
            const size_t grow = (size_t)(qt * 128 + lrow);
            float s[4];
#pragma unroll
            for (int ni = 0; ni < 4; ni++) {
                const int lcol = nw + ni * 16 + fr;
                float v = acc[mi][ni][r] * SCALE;
                if (fuse && Ms[lrow][lcol]) v = NEG_BIG;
                s[ni] = v;
                ScB[grow * S + kt * 128 + lcol] = v;
            }
            if (fuse) {
                float mx = fmaxf(fmaxf(s[0], s[1]), fmaxf(s[2], s[3]));
#pragma unroll
                for (int o = 8; o > 0; o >>= 1) mx = fmaxf(mx, __shfl_xor(mx, o, 64));
                float lsum = __expf(s[0] - mx) + __expf(s[1] - mx) +
                             __expf(s[2] - mx) + __expf(s[3] - mx);
#pragma unroll
                for (int o = 8; o > 0; o >>= 1) lsum += __shfl_xor(lsum, o, 64);
                if (fr == 0) pm[lrow * 2 + (w & 1)] = make_float2(mx, lsum);
            }
        }

    if (fuse) {
        __syncthreads();
        if (t < 128) {
            float2 a = pm[t * 2 + 0], c = pm[t * 2 + 1];
            float M = fmaxf(a.x, c.x);
            float L = a.y * __expf(a.x - M) + c.y * __expf(c.x - M);
            part[((size_t)(b * 16 + kt)) * S + qt * 128 + t] = make_float2(M, L);
        }
    }
}

__global__ __launch_bounds__(256) void softmax_kernel(float* __restrict__ Sc,
                                                      const void* __restrict__ maskp,
                                                      const int* __restrict__ flagp) {
    const int b = blockIdx.y;
    const int w = threadIdx.x >> 6, lane = threadIdx.x & 63;
    const int row = blockIdx.x * 4 + w;
    float* R = Sc + ((size_t)b * S + row) * S;
    float4* R4 = (float4*)R;
    const int flag = flagp ? *flagp : 0;

    float sv[32];
    if (flag) {
        const uchar4* M4 = (const uchar4*)((const unsigned char*)maskp + ((size_t)b * S + row) * S);
#pragma unroll
        for (int j = 0; j < 8; j++) {
            float4 v = R4[lane + 64 * j];
            uchar4 mv = M4[lane + 64 * j];
            sv[4 * j + 0] = mv.x ? NEG_BIG : v.x;
            sv[4 * j + 1] = mv.y ? NEG_BIG : v.y;
            sv[4 * j + 2] = mv.z ? NEG_BIG : v.z;
            sv[4 * j + 3] = mv.w ? NEG_BIG : v.w;
        }
    } else {
        const int4* M4 = (const int4*)((const int*)maskp + ((size_t)b * S + row) * S);
#pragma unroll
        for (int j = 0; j < 8; j++) {
            float4 v = R4[lane + 64 * j];
            int4 mv = M4[lane + 64 * j];
            sv[4 * j + 0] = mv.x ? NEG_BIG : v.x;
            sv[4 * j + 1] = mv.y ? NEG_BIG : v.y;
            sv[4 * j + 2] = mv.z ? NEG_BIG : v.z;
            sv[4 * j + 3] = mv.w ? NEG_BIG : v.w;
        }
    }

    float mx = sv[0];
#pragma unroll
    for (int i = 1; i < 32; i++) mx = fmaxf(mx, sv[i]);
    for (int o = 32; o > 0; o >>= 1) mx = fmaxf(mx, __shfl_xor(mx, o, 64));

    float sum = 0.f;
#pragma unroll
    for (int i = 0; i < 32; i++) {
        sv[i] = __expf(sv[i] - mx);
        sum += sv[i];
    }
    for (int o = 32; o > 0; o >>= 1) sum += __shfl_xor(sum, o, 64);
    const float inv = 1.0f / sum;

#pragma unroll
    for (int j = 0; j < 8; j++) {
        float4 p;
        p.x = sv[4 * j + 0] * inv;
        p.y = sv[4 * j + 1] * inv;
        p.z = sv[4 * j + 2] * inv;
        p.w = sv[4 * j + 3] * inv;
        R4[lane + 64 * j] = p;
    }
}

__global__ __launch_bounds__(256, 2) void pv_kernel(float* __restrict__ Sc,
                                                    const float* __restrict__ V,
                                                    const short* __restrict__ Vt,
                                                    const int useVt,
                                                    float* __restrict__ Out,
                                                    const float2* __restrict__ stats,
                                                    const int fuse) {
    const int mt = blockIdx.x, b = blockIdx.y;
    float* ScB = Sc + (size_t)b * S * S + (size_t)mt * 64 * S;
    const float* Vb = V + (size_t)b * S * Dh;
    const short* VtB = Vt + (size_t)b * Dh * S;
    float* OutB = Out + ((size_t)b * S + mt * 64) * Dh;
    __shared__ short As[64][72];
    __shared__ float2 sstat[64];
    const int t = threadIdx.x, w = t >> 6, lane = t & 63, fr = lane & 15, quad = lane >> 4;
    const int mw = (w >> 1) * 32, nw = (w & 1) * 64;
    f32x4 acc[2][4] = {};

    if (fuse && t < 64) sstat[t] = stats[(size_t)b * S + mt * 64 + t];

    for (int k0 = 0; k0 < S; k0 += 64) {
        __syncthreads();
#pragma unroll
        for (int i = 0; i < 4; i++) {
            int idx = t + i * 256;
            int r = idx >> 4, c = (idx & 15) << 2;
            float4 v = *(const float4*)(ScB + (size_t)r * S + k0 + c);
            if (fuse) {
                float2 stv = sstat[r];
                v.x = __expf(v.x - stv.x) * stv.y;
                v.y = __expf(v.y - stv.x) * stv.y;
                v.z = __expf(v.z - stv.x) * stv.y;
                v.w = __expf(v.w - stv.x) * stv.y;
                *(float4*)(ScB + (size_t)r * S + k0 + c) = v;
            }
            *(s16x4*)&As[r][c] = pack4(v);
        }
        __syncthreads();
#pragma unroll
        for (int kc = 0; kc < 2; kc++) {
            const int ko = kc * 32 + quad * 8;
            bf16x8 af[2], bf[4];
#pragma unroll
            for (int mi = 0; mi < 2; mi++) af[mi] = *(const bf16x8*)&As[mw + mi * 16 + fr][ko];
            if (useVt) {
#pragma unroll
                for (int ni = 0; ni < 4; ni++)
                    bf[ni] = *(const bf16x8*)(VtB + (size_t)(nw + ni * 16 + fr) * S + k0 + ko);
            } else {
#pragma unroll
                for (int ni = 0; ni < 4; ni++) {
                    int n = nw + ni * 16 + fr;
#pragma unroll
                    for (int j = 0; j < 8; j++) bf[ni][j] = f2bf(Vb[(size_t)(k0 + ko + j) * Dh + n]);
                }
            }
#pragma unroll
            for (int mi = 0; mi < 2; mi++)
#pragma unroll
                for (int ni = 0; ni < 4; ni++)
                    acc[mi][ni] = __builtin_amdgcn_mfma_f32_16x16x32_bf16(af[mi], bf[ni], acc[mi][ni], 0, 0, 0);
        }
    }

#pragma unroll
    for (int mi = 0; mi < 2; mi++)
#pragma unroll
        for (int ni = 0; ni < 4; ni++)
#pragma unroll
            for (int r = 0; r < 4; r++) {
                int row = mw + mi * 16 + quad * 4 + r;
                int col = nw + ni * 16 + fr;
                OutB[(size_t)row * Dh + col] = acc[mi][ni][r];
            }
}

extern "C" void kernel_launch(void* const* d_in, const int* in_sizes, int n_in,
                              void* d_out, int out_size, void* d_ws, size_t ws_size,
                              hipStream_t stream) {
    const float* Q = (const float*)d_in[0];
    const float* Km = (const float*)d_in[1];
    const float* V = (const float*)d_in[2];
    const void* M = d_in[3];
    float* out = (float*)d_out;
    float* attn = out + OUT_ELEMS;

    const size_t VT_BYTES   = (size_t)NB * Dh * S * sizeof(short);   // 8 MB
    const size_t QBF_BYTES  = (size_t)NB * S * Dh * sizeof(short);   // 8 MB
    const size_t KBF_BYTES  = QBF_BYTES;                             // 8 MB
    const size_t STATS_BYTES = (size_t)NB * S * sizeof(float2);      // 256 KB
    const size_t REQ_NEW = VT_BYTES + QBF_BYTES + KBF_BYTES + STATS_BYTES + 64;

    if (ws_size >= REQ_NEW) {
        short* Vt   = (short*)d_ws;
        short* Qbf  = (short*)((char*)d_ws + VT_BYTES);
        short* Kbf  = (short*)((char*)d_ws + VT_BYTES + QBF_BYTES);
        float2* stats = (float2*)((char*)d_ws + VT_BYTES + QBF_BYTES + KBF_BYTES);
        int* flag = (int*)((char*)d_ws + VT_BYTES + QBF_BYTES + KBF_BYTES + STATS_BYTES);

        prep<<<1537, 256, 0, stream>>>(Q, Km, V, (const unsigned char*)M, Qbf, Kbf, Vt, flag);
        flash_pv<<<512, 256, 0, stream>>>(Qbf, Kbf, Vt, M, flag, stats, out);
        attn_write<<<4096, 256, 0, stream>>>(Qbf, Kbf, M, flag, stats, attn);
        return;
    }

    // ---------------- fallback: verified round-2 path ----------------
    float2* part = (float2*)d_out;   // 4 MB partials in the out region
    int useVt = 0, fuse = 0;
    short* Vt = nullptr;
    float2* stats = nullptr;
    int* flag = nullptr;

    if (ws_size >= VT_BYTES + STATS_BYTES + 64) {
        useVt = 1; fuse = 1;
        Vt = (short*)d_ws;
        stats = (float2*)((char*)d_ws + VT_BYTES);
        flag = (int*)((char*)d_ws + VT_BYTES + STATS_BYTES);
    } else if (ws_size >= VT_BYTES + 64) {
        useVt = 1;
        Vt = (short*)d_ws;
        flag = (int*)((char*)d_ws + VT_BYTES);
    } else if (ws_size >= 64) {
        flag = (int*)d_ws;
    }

    if (flag) detect_mask<<<1, 256, 0, stream>>>((const unsigned char*)M, flag);
    if (useVt) transpose_v<<<dim3(32, NB), 256, 0, stream>>>(V, Vt);

    qk_kernel<<<dim3(16, 16, NB), 256, 0, stream>>>(Q, Km, attn, M, flag, part, fuse);

    if (fuse) {
        reduce_stats<<<dim3((NB * S) / 256), 256, 0, stream>>>(part, stats);
        pv_kernel<<<dim3(32, NB), 256, 0, stream>>>(attn, V, Vt, useVt, out, stats, 1);
    } else {
        softmax_kernel<<<dim3(512, NB), 256, 0, stream>>>(attn, M, flag);
        pv_kernel<<<dim3(32, NB), 256, 0, stream>>>(attn, V, Vt, useVt, out, nullptr, 0);
    }
}